// Round 9
// baseline (587.488 us; speedup 1.0000x reference)
//
#include <hip/hip_runtime.h>

#define N_NODES 32768
#define C_IN 128
#define C_W 32
#define KK 24
#define SS 5
#define GG 8                 // nodes per k_node block (one per wave)
#define AGS (KK * C_W + 4)   // padded sAgg stride
#define WNS 172              // padded weightnet W stride (168+4)
#define WBS 28               // padded weightnet bias stride (24+4)

// ---------------- colstats(x) for BN1 + edge histogram ----------------
__global__ void __launch_bounds__(256) k_pre(
        const float* __restrict__ x, float* __restrict__ s1,
        const int* __restrict__ ei, int E, int* __restrict__ counts) {
    int t = threadIdx.x;
    int c = t % C_IN;
    int r0 = blockIdx.x * 2 + t / C_IN;
    float s = 0.f, sq = 0.f;
    for (int r = r0; r < N_NODES; r += 1024) {
        float v = x[(size_t)r * C_IN + c];
        s += v; sq += v * v;
    }
    atomicAdd(&s1[c], s);
    atomicAdd(&s1[C_IN + c], sq);
    for (int e = blockIdx.x * 256 + t; e < E; e += 512 * 256)
        atomicAdd(&counts[ei[E + e]], 1);
}

// ---------------- input MLP: lrelu(bn1(x)) @ lin1_w (+ BN2 stats) ----------------
__global__ void __launch_bounds__(256) k_mlp1(
        const float* __restrict__ x, const float* __restrict__ s1,
        const float* __restrict__ g1, const float* __restrict__ b1,
        const float* __restrict__ w1, float* __restrict__ hpre,
        float* __restrict__ s2sh) {
    __shared__ float sAB[2][C_IN];
    __shared__ float sx[32][C_IN + 4];
    __shared__ float sw[C_IN][C_W];
    const int t = threadIdx.x;
    const int row0 = blockIdx.x * 32;
    if (t < C_IN) {
        float mean = s1[t] * (1.f / N_NODES);
        float var = s1[C_IN + t] * (1.f / N_NODES) - mean * mean;
        float a = g1[t] * rsqrtf(var + 1e-5f);
        sAB[0][t] = a; sAB[1][t] = b1[t] - mean * a;
    }
    for (int idx = t; idx < C_IN * C_W; idx += 256)
        sw[idx / C_W][idx % C_W] = w1[idx];
    __syncthreads();
    for (int idx = t; idx < 32 * 32; idx += 256) {
        int r = idx >> 5, cq = idx & 31;
        float4 v = *(const float4*)&x[(size_t)(row0 + r) * C_IN + cq * 4];
        float* d = &sx[r][cq * 4];
        float a0 = sAB[0][cq*4+0]*v.x + sAB[1][cq*4+0];
        float a1 = sAB[0][cq*4+1]*v.y + sAB[1][cq*4+1];
        float a2 = sAB[0][cq*4+2]*v.z + sAB[1][cq*4+2];
        float a3 = sAB[0][cq*4+3]*v.w + sAB[1][cq*4+3];
        d[0] = a0 >= 0.f ? a0 : 0.1f * a0;
        d[1] = a1 >= 0.f ? a1 : 0.1f * a1;
        d[2] = a2 >= 0.f ? a2 : 0.1f * a2;
        d[3] = a3 >= 0.f ? a3 : 0.1f * a3;
    }
    __syncthreads();
    const int r = t >> 3, c0 = (t & 7) * 4;
    float ac0 = 0.f, ac1 = 0.f, ac2 = 0.f, ac3 = 0.f;
    #pragma unroll 8
    for (int cc = 0; cc < C_IN; ++cc) {
        float xv = sx[r][cc];
        float4 wv = *(const float4*)&sw[cc][c0];
        ac0 += xv * wv.x; ac1 += xv * wv.y; ac2 += xv * wv.z; ac3 += xv * wv.w;
    }
    float4 o; o.x = ac0; o.y = ac1; o.z = ac2; o.w = ac3;
    *(float4*)&hpre[(size_t)(row0 + r) * C_W + c0] = o;
    __syncthreads();
    sx[r][c0] = ac0; sx[r][c0+1] = ac1; sx[r][c0+2] = ac2; sx[r][c0+3] = ac3;
    __syncthreads();
    if (t < C_W) {
        float s = 0.f, sq = 0.f;
        #pragma unroll
        for (int rr = 0; rr < 32; ++rr) {
            float v = sx[rr][t];
            s += v; sq += v * v;
        }
        int sh = (blockIdx.x & 7) * 64;
        atomicAdd(&s2sh[sh + t], s);
        atomicAdd(&s2sh[sh + C_W + t], sq);
    }
}

// ---------------- single-block scan (1024 thr x 32 elems, int4) ----------------
__global__ void __launch_bounds__(1024) k_scan(
        const int* __restrict__ counts, int* __restrict__ offsets,
        int* __restrict__ cursor) {
    __shared__ int sblk[1024];
    const int t = threadIdx.x;
    const int base = t * 32;
    const int4* cp = (const int4*)(counts + base);
    int loc[32];
    int s = 0;
    #pragma unroll
    for (int q = 0; q < 8; ++q) {
        int4 v = cp[q];
        loc[q*4+0] = s; s += v.x;
        loc[q*4+1] = s; s += v.y;
        loc[q*4+2] = s; s += v.z;
        loc[q*4+3] = s; s += v.w;
    }
    sblk[t] = s;
    __syncthreads();
    for (int d = 1; d < 1024; d <<= 1) {
        int u = (t >= d) ? sblk[t - d] : 0;
        __syncthreads();
        sblk[t] += u;
        __syncthreads();
    }
    const int blockbase = sblk[t] - s;
    #pragma unroll
    for (int q = 0; q < 8; ++q) {
        int4 o;
        o.x = blockbase + loc[q*4+0];
        o.y = blockbase + loc[q*4+1];
        o.z = blockbase + loc[q*4+2];
        o.w = blockbase + loc[q*4+3];
        ((int4*)(offsets + base))[q] = o;
        ((int4*)(cursor + base))[q] = o;
    }
    if (t == 1023) offsets[N_NODES] = sblk[1023];
}

// ---------------- scatter: CSR permutation of src indices ----------------
__global__ void __launch_bounds__(256) k_scatter(
        const int* __restrict__ ei, int E, int* __restrict__ cursor,
        int* __restrict__ srcPerm) {
    int e = blockIdx.x * 256 + threadIdx.x;
    if (e < E) {
        int dst = ei[E + e];
        int p = atomicAdd(&cursor[dst], 1);
        srcPerm[p] = ei[e];
    }
}

// ---------------- fused: WeightNet + aggregation + projection (+ BN3 stats) ----
// 512 threads = 8 waves; one node per wave. Per 32-edge chunk:
// lane e computes delta+WeightNet for its edge (12 k's per half), packs w to
// bf16 in LDS; h rows preloaded into 16 regs; FMA phase 2 LDS reads/edge.
__global__ void __launch_bounds__(512, 4) k_node(
    const int* __restrict__ offsets, const int* __restrict__ srcPerm,
    const float* __restrict__ pos, const float* __restrict__ ori,
    const int* __restrict__ seq, const float* __restrict__ hpre,
    const float* __restrict__ s2sh, const float* __restrict__ g2,
    const float* __restrict__ b2,
    const float* __restrict__ wnw, const float* __restrict__ wnb,
    const float* __restrict__ convw,
    float* __restrict__ convout, float* __restrict__ s3sh) {

    __shared__ float sA2[C_W], sB2[C_W];
    __shared__ int sOff[GG + 1];
    __shared__ float sWnw[11 * WNS];
    __shared__ float sWnb[11 * WBS];
    __shared__ unsigned int sWp[GG][32 * 16];   // packed bf16 w, 64B/edge
    __shared__ float sAgg[GG][AGS];
    __shared__ float sRed[8][GG][C_W];
    __shared__ float sRv[GG][C_W], sRq[GG][C_W];

    const int t = threadIdx.x;
    const int i0 = blockIdx.x * GG;
    for (int idx = t; idx < 11 * 168; idx += 512)
        sWnw[(idx / 168) * WNS + idx % 168] = wnw[idx];
    for (int idx = t; idx < 11 * 24; idx += 512)
        sWnb[(idx / 24) * WBS + idx % 24] = wnb[idx];
    if (t < C_W) {
        float s = 0.f, sq = 0.f;
        #pragma unroll
        for (int j = 0; j < 8; ++j) {
            s  += s2sh[j * 64 + t];
            sq += s2sh[j * 64 + C_W + t];
        }
        float mean = s * (1.f / N_NODES);
        float var = sq * (1.f / N_NODES) - mean * mean;
        float a = g2[t] * rsqrtf(var + 1e-5f);
        sA2[t] = a; sB2[t] = b2[t] - mean * a;
    }
    if (t <= GG) sOff[t] = offsets[i0 + t];
    __syncthreads();

    const int w = t >> 6, lane = t & 63, c = lane & 31, s = lane >> 5;
    const int i = i0 + w;
    const float bnA = sA2[c], bnB = sB2[c];
    const float pi0 = pos[i*3+0], pi1 = pos[i*3+1], pi2 = pos[i*3+2];
    float Rm[9];
    #pragma unroll
    for (int r = 0; r < 9; ++r) Rm[r] = ori[i*9+r];
    const int si = seq[i];
    const int beg = sOff[w], end = sOff[w + 1];
    unsigned int* sWw = &sWp[w][0];
    float a[12];
    #pragma unroll
    for (int j = 0; j < 12; ++j) a[j] = 0.f;

    for (int cb = beg; cb < end; cb += 32) {
        const int m = min(32, end - cb);
        const int src = srcPerm[cb + min(c, m - 1)];
        // ---- h preload: 16 reg loads (edge 2q+s at channel c) ----
        float hr[16];
        #pragma unroll
        for (int q = 0; q < 16; ++q) {
            int ee = min(2 * q + s, m - 1);
            int sq_ = __shfl(src, ee, 32);
            hr[q] = hpre[(size_t)sq_ * C_W + c];
        }
        // ---- delta for my edge (e = c; both halves duplicate) ----
        float px = pos[src*3+0], py = pos[src*3+1], pz = pos[src*3+2];
        float o0 = ori[src*9+0], o1 = ori[src*9+1], o2 = ori[src*9+2];
        int sqs = seq[src];
        float dx = px - pi0, dy = py - pi1, dz = pz - pi2;
        float dist = sqrtf(dx*dx + dy*dy + dz*dz);
        float inv = 1.f / (dist + 1e-9f);
        float ux = dx*inv, uy = dy*inv, uz = dz*inv;
        float df[7];
        df[0] = Rm[0]*ux + Rm[1]*uy + Rm[2]*uz;
        df[1] = Rm[3]*ux + Rm[4]*uy + Rm[5]*uz;
        df[2] = Rm[6]*ux + Rm[7]*uy + Rm[8]*uz;
        df[3] = Rm[0]*o0 + Rm[1]*o1 + Rm[2]*o2;
        df[4] = Rm[3]*o0 + Rm[4]*o1 + Rm[5]*o2;
        df[5] = Rm[6]*o0 + Rm[7]*o1 + Rm[8]*o2;
        df[6] = dist * 0.125f;
        int dsq = sqs - si; dsq = dsq < -SS ? -SS : (dsq > SS ? SS : dsq);
        const int sb = dsq + SS;
        // ---- WeightNet: my edge, k in [12s, 12s+12) ----
        float wv[12];
        {
            const float* wb = &sWnb[sb * WBS + s * 12];
            float4 b0 = *(const float4*)&wb[0];
            float4 b1 = *(const float4*)&wb[4];
            float4 b2_ = *(const float4*)&wb[8];
            wv[0]=b0.x; wv[1]=b0.y; wv[2]=b0.z; wv[3]=b0.w;
            wv[4]=b1.x; wv[5]=b1.y; wv[6]=b1.z; wv[7]=b1.w;
            wv[8]=b2_.x; wv[9]=b2_.y; wv[10]=b2_.z; wv[11]=b2_.w;
        }
        const float* wn = &sWnw[sb * WNS + s * 12];
        #pragma unroll
        for (int f = 0; f < 7; ++f) {
            float4 q0 = *(const float4*)&wn[f*24 + 0];
            float4 q1 = *(const float4*)&wn[f*24 + 4];
            float4 q2 = *(const float4*)&wn[f*24 + 8];
            float d_ = df[f];
            wv[0]+=d_*q0.x; wv[1]+=d_*q0.y; wv[2]+=d_*q0.z; wv[3]+=d_*q0.w;
            wv[4]+=d_*q1.x; wv[5]+=d_*q1.y; wv[6]+=d_*q1.z; wv[7]+=d_*q1.w;
            wv[8]+=d_*q2.x; wv[9]+=d_*q2.y; wv[10]+=d_*q2.z; wv[11]+=d_*q2.w;
        }
        #pragma unroll
        for (int j = 0; j < 12; ++j) wv[j] = wv[j] >= 0.f ? wv[j] : 0.2f * wv[j];
        // ---- pack bf16 pairs, write 24B to my edge slot ----
        unsigned int pk[6];
        #pragma unroll
        for (int jj = 0; jj < 6; ++jj) {
            unsigned int ulo = __float_as_uint(wv[2*jj]);
            unsigned int uhi = __float_as_uint(wv[2*jj+1]);
            ulo = (ulo + 0x7FFFu + ((ulo >> 16) & 1u)) >> 16;
            uhi = (uhi + 0x7FFFu + ((uhi >> 16) & 1u)) & 0xFFFF0000u;
            pk[jj] = uhi | ulo;
        }
        {
            uint4 w4; w4.x = pk[0]; w4.y = pk[1]; w4.z = pk[2]; w4.w = pk[3];
            *(uint4*)&sWw[c * 16 + s * 8] = w4;
            uint2 w2_; w2_.x = pk[4]; w2_.y = pk[5];
            *(uint2*)&sWw[c * 16 + s * 8 + 4] = w2_;
        }
        // ---- BN2 + lrelu + mask on preloaded h ----
        #pragma unroll
        for (int q = 0; q < 16; ++q) {
            float v = bnA * hr[q] + bnB;
            v = v >= 0.f ? v : 0.1f * v;
            hr[q] = (2 * q + s < m) ? v : 0.f;
        }
        // ---- FMA phase: 32 edges, 2 per q ----
        #pragma unroll
        for (int q = 0; q < 16; ++q) {
            float oth = __shfl_xor(hr[q], 32);
            float v0 = (s == 0) ? hr[q] : oth;   // edge 2q
            float v1 = (s == 0) ? oth : hr[q];   // edge 2q+1
            {
                uint4 pA = *(const uint4*)&sWw[(2*q) * 16 + s * 8];
                uint2 pB = *(const uint2*)&sWw[(2*q) * 16 + s * 8 + 4];
                a[0]  += __uint_as_float(pA.x << 16) * v0;
                a[1]  += __uint_as_float(pA.x & 0xFFFF0000u) * v0;
                a[2]  += __uint_as_float(pA.y << 16) * v0;
                a[3]  += __uint_as_float(pA.y & 0xFFFF0000u) * v0;
                a[4]  += __uint_as_float(pA.z << 16) * v0;
                a[5]  += __uint_as_float(pA.z & 0xFFFF0000u) * v0;
                a[6]  += __uint_as_float(pA.w << 16) * v0;
                a[7]  += __uint_as_float(pA.w & 0xFFFF0000u) * v0;
                a[8]  += __uint_as_float(pB.x << 16) * v0;
                a[9]  += __uint_as_float(pB.x & 0xFFFF0000u) * v0;
                a[10] += __uint_as_float(pB.y << 16) * v0;
                a[11] += __uint_as_float(pB.y & 0xFFFF0000u) * v0;
            }
            {
                uint4 pA = *(const uint4*)&sWw[(2*q+1) * 16 + s * 8];
                uint2 pB = *(const uint2*)&sWw[(2*q+1) * 16 + s * 8 + 4];
                a[0]  += __uint_as_float(pA.x << 16) * v1;
                a[1]  += __uint_as_float(pA.x & 0xFFFF0000u) * v1;
                a[2]  += __uint_as_float(pA.y << 16) * v1;
                a[3]  += __uint_as_float(pA.y & 0xFFFF0000u) * v1;
                a[4]  += __uint_as_float(pA.z << 16) * v1;
                a[5]  += __uint_as_float(pA.z & 0xFFFF0000u) * v1;
                a[6]  += __uint_as_float(pA.w << 16) * v1;
                a[7]  += __uint_as_float(pA.w & 0xFFFF0000u) * v1;
                a[8]  += __uint_as_float(pB.x << 16) * v1;
                a[9]  += __uint_as_float(pB.x & 0xFFFF0000u) * v1;
                a[10] += __uint_as_float(pB.y << 16) * v1;
                a[11] += __uint_as_float(pB.y & 0xFFFF0000u) * v1;
            }
        }
    }
    #pragma unroll
    for (int j = 0; j < 12; ++j) sAgg[w][(s * 12 + j) * C_W + c] = a[j];
    __syncthreads();

    // projection: t = sl8*64 + gp*8 + coq ; each thread 96 rows x 4 cols
    {
        const int coq = t & 7;
        const int gp  = (t >> 3) & 7;
        const int sl8 = t >> 6;
        const int r0  = sl8 * 96;
        float4 acc; acc.x = acc.y = acc.z = acc.w = 0.f;
        #pragma unroll 6
        for (int rc = 0; rc < 96; rc += 4) {
            const float4 s4 = *(const float4*)&sAgg[gp][r0 + rc];
            const float4 w0 = *(const float4*)&convw[(size_t)(r0+rc+0)*32 + coq*4];
            const float4 w1 = *(const float4*)&convw[(size_t)(r0+rc+1)*32 + coq*4];
            const float4 w2 = *(const float4*)&convw[(size_t)(r0+rc+2)*32 + coq*4];
            const float4 w3 = *(const float4*)&convw[(size_t)(r0+rc+3)*32 + coq*4];
            acc.x += s4.x*w0.x + s4.y*w1.x + s4.z*w2.x + s4.w*w3.x;
            acc.y += s4.x*w0.y + s4.y*w1.y + s4.z*w2.y + s4.w*w3.y;
            acc.z += s4.x*w0.z + s4.y*w1.z + s4.z*w2.z + s4.w*w3.z;
            acc.w += s4.x*w0.w + s4.y*w1.w + s4.z*w2.w + s4.w*w3.w;
        }
        *(float4*)&sRed[sl8][gp][coq * 4] = acc;
    }
    __syncthreads();
    if (t < 256) {
        const int gg = t >> 5, co = t & 31;
        float v = 0.f;
        #pragma unroll
        for (int sl = 0; sl < 8; ++sl) v += sRed[sl][gg][co];
        convout[(size_t)(i0 + gg) * C_W + co] = v;
        sRv[gg][co] = v; sRq[gg][co] = v * v;
    }
    __syncthreads();
    if (t < 64) {
        int cc = t & 31;
        bool isq = t >= C_W;
        float s2 = 0.f;
        #pragma unroll
        for (int gg = 0; gg < GG; ++gg)
            s2 += isq ? sRq[gg][cc] : sRv[gg][cc];
        atomicAdd(&s3sh[(blockIdx.x & 7) * 64 + t], s2);
    }
}

// ---------------- output: lrelu(bn3(conv)) @ lin2_w + x (float4) ----------------
__global__ void __launch_bounds__(256) k_out(
        const float* __restrict__ conv, const float* __restrict__ s3sh,
        const float* __restrict__ g3, const float* __restrict__ b3,
        const float* __restrict__ w2, const float* __restrict__ x,
        float* __restrict__ out) {
    __shared__ float sAB[2][C_W];
    __shared__ float sh[8][C_W];
    __shared__ float sw2[C_W][C_IN];
    const int t = threadIdx.x;
    const int row0 = blockIdx.x * 8;
    if (t < C_W) {
        float s = 0.f, sq = 0.f;
        #pragma unroll
        for (int j = 0; j < 8; ++j) {
            s  += s3sh[j * 64 + t];
            sq += s3sh[j * 64 + C_W + t];
        }
        float mean = s * (1.f / N_NODES);
        float var = sq * (1.f / N_NODES) - mean * mean;
        float a = g3[t] * rsqrtf(var + 1e-5f);
        sAB[0][t] = a; sAB[1][t] = b3[t] - mean * a;
    }
    for (int idx = t; idx < C_W * C_IN; idx += 256)
        sw2[idx >> 7][idx & 127] = w2[idx];
    __syncthreads();
    {
        float v = conv[(size_t)row0 * C_W + t];
        int r = t >> 5, cc = t & 31;
        v = sAB[0][cc] * v + sAB[1][cc];
        sh[r][cc] = v >= 0.f ? v : 0.1f * v;
    }
    __syncthreads();
    const int r = t >> 5, c4 = (t & 31) * 4;
    float4 acc = *(const float4*)&x[(size_t)(row0 + r) * C_IN + c4];
    #pragma unroll 8
    for (int cw = 0; cw < C_W; ++cw) {
        float hv = sh[r][cw];
        float4 wv = *(const float4*)&sw2[cw][c4];
        acc.x += hv * wv.x; acc.y += hv * wv.y;
        acc.z += hv * wv.z; acc.w += hv * wv.w;
    }
    *(float4*)&out[(size_t)(row0 + r) * C_IN + c4] = acc;
}

extern "C" void kernel_launch(void* const* d_in, const int* in_sizes, int n_in,
                              void* d_out, int out_size, void* d_ws, size_t ws_size,
                              hipStream_t stream) {
    const float* x     = (const float*)d_in[0];
    const float* pos   = (const float*)d_in[1];
    const float* ori   = (const float*)d_in[2];
    const int*   seq   = (const int*)d_in[3];
    const int*   ei    = (const int*)d_in[4];
    const float* bn1g  = (const float*)d_in[5];
    const float* bn1b  = (const float*)d_in[6];
    const float* lin1w = (const float*)d_in[7];
    const float* bn2g  = (const float*)d_in[8];
    const float* bn2b  = (const float*)d_in[9];
    const float* wnw   = (const float*)d_in[10];
    const float* wnb   = (const float*)d_in[11];
    const float* convw = (const float*)d_in[12];
    const float* bn3g  = (const float*)d_in[13];
    const float* bn3b  = (const float*)d_in[14];
    const float* lin2w = (const float*)d_in[15];
    float* out = (float*)d_out;
    const int E = in_sizes[4] / 2;

    char* wsb = (char*)d_ws;
    size_t off = 0;
    auto alloc = [&](size_t bytes) {
        void* p = wsb + off;
        off = (off + bytes + 255) & ~(size_t)255;
        return p;
    };
    float* s1      = (float*)alloc(256 * 4);
    float* s2sh    = (float*)alloc(512 * 4);
    float* s3sh    = (float*)alloc(512 * 4);
    int*   counts  = (int*)alloc((size_t)N_NODES * 4);
    size_t zero_bytes = off;
    int*   offsets = (int*)alloc(((size_t)N_NODES + 1) * 4);
    int*   cursor  = (int*)alloc((size_t)N_NODES * 4);
    int*   srcPerm = (int*)alloc((size_t)E * 4);
    float* hpre    = (float*)alloc((size_t)N_NODES * C_W * 4);
    float* convo   = (float*)alloc((size_t)N_NODES * C_W * 4);

    hipMemsetAsync(wsb, 0, zero_bytes, stream);

    k_pre<<<512, 256, 0, stream>>>(x, s1, ei, E, counts);
    k_scan<<<1, 1024, 0, stream>>>(counts, offsets, cursor);
    k_scatter<<<(E + 255) / 256, 256, 0, stream>>>(ei, E, cursor, srcPerm);
    k_mlp1<<<N_NODES / 32, 256, 0, stream>>>(x, s1, bn1g, bn1b, lin1w, hpre, s2sh);
    k_node<<<N_NODES / GG, 512, 0, stream>>>(offsets, srcPerm, pos, ori, seq,
                                             hpre, s2sh, bn2g, bn2b, wnw, wnb,
                                             convw, convo, s3sh);
    k_out<<<N_NODES / 8, 256, 0, stream>>>(convo, s3sh, bn3g, bn3b, lin2w, x, out);
}

// Round 10
// 451.273 us; speedup vs baseline: 1.3018x; 1.3018x over previous
//
#include <hip/hip_runtime.h>

#define N_NODES 32768
#define C_IN 128
#define C_W 32
#define KK 24
#define SS 5
#define GG 8                 // nodes per k_node block (one per wave)
#define AGS (KK * C_W + 4)   // padded sAgg stride
#define WNS 172              // padded weightnet W stride (168+4)
#define WBS 28               // padded weightnet bias stride (24+4)
#define EPS 17               // padded per-edge stride in sWp (uints)

// ---------------- colstats(x) for BN1 + edge histogram ----------------
__global__ void __launch_bounds__(256) k_pre(
        const float* __restrict__ x, float* __restrict__ s1,
        const int* __restrict__ ei, int E, int* __restrict__ counts) {
    int t = threadIdx.x;
    int c = t % C_IN;
    int r0 = blockIdx.x * 2 + t / C_IN;
    float s = 0.f, sq = 0.f;
    for (int r = r0; r < N_NODES; r += 1024) {
        float v = x[(size_t)r * C_IN + c];
        s += v; sq += v * v;
    }
    atomicAdd(&s1[c], s);
    atomicAdd(&s1[C_IN + c], sq);
    for (int e = blockIdx.x * 256 + t; e < E; e += 512 * 256)
        atomicAdd(&counts[ei[E + e]], 1);
}

// ---------------- input MLP: lrelu(bn1(x)) @ lin1_w (+ BN2 stats) ----------------
__global__ void __launch_bounds__(256) k_mlp1(
        const float* __restrict__ x, const float* __restrict__ s1,
        const float* __restrict__ g1, const float* __restrict__ b1,
        const float* __restrict__ w1, float* __restrict__ hpre,
        float* __restrict__ s2sh) {
    __shared__ float sAB[2][C_IN];
    __shared__ float sx[32][C_IN + 4];
    __shared__ float sw[C_IN][C_W];
    const int t = threadIdx.x;
    const int row0 = blockIdx.x * 32;
    if (t < C_IN) {
        float mean = s1[t] * (1.f / N_NODES);
        float var = s1[C_IN + t] * (1.f / N_NODES) - mean * mean;
        float a = g1[t] * rsqrtf(var + 1e-5f);
        sAB[0][t] = a; sAB[1][t] = b1[t] - mean * a;
    }
    for (int idx = t; idx < C_IN * C_W; idx += 256)
        sw[idx / C_W][idx % C_W] = w1[idx];
    __syncthreads();
    for (int idx = t; idx < 32 * 32; idx += 256) {
        int r = idx >> 5, cq = idx & 31;
        float4 v = *(const float4*)&x[(size_t)(row0 + r) * C_IN + cq * 4];
        float* d = &sx[r][cq * 4];
        float a0 = sAB[0][cq*4+0]*v.x + sAB[1][cq*4+0];
        float a1 = sAB[0][cq*4+1]*v.y + sAB[1][cq*4+1];
        float a2 = sAB[0][cq*4+2]*v.z + sAB[1][cq*4+2];
        float a3 = sAB[0][cq*4+3]*v.w + sAB[1][cq*4+3];
        d[0] = a0 >= 0.f ? a0 : 0.1f * a0;
        d[1] = a1 >= 0.f ? a1 : 0.1f * a1;
        d[2] = a2 >= 0.f ? a2 : 0.1f * a2;
        d[3] = a3 >= 0.f ? a3 : 0.1f * a3;
    }
    __syncthreads();
    const int r = t >> 3, c0 = (t & 7) * 4;
    float ac0 = 0.f, ac1 = 0.f, ac2 = 0.f, ac3 = 0.f;
    #pragma unroll 8
    for (int cc = 0; cc < C_IN; ++cc) {
        float xv = sx[r][cc];
        float4 wv = *(const float4*)&sw[cc][c0];
        ac0 += xv * wv.x; ac1 += xv * wv.y; ac2 += xv * wv.z; ac3 += xv * wv.w;
    }
    float4 o; o.x = ac0; o.y = ac1; o.z = ac2; o.w = ac3;
    *(float4*)&hpre[(size_t)(row0 + r) * C_W + c0] = o;
    __syncthreads();
    sx[r][c0] = ac0; sx[r][c0+1] = ac1; sx[r][c0+2] = ac2; sx[r][c0+3] = ac3;
    __syncthreads();
    if (t < C_W) {
        float s = 0.f, sq = 0.f;
        #pragma unroll
        for (int rr = 0; rr < 32; ++rr) {
            float v = sx[rr][t];
            s += v; sq += v * v;
        }
        int sh = (blockIdx.x & 7) * 64;
        atomicAdd(&s2sh[sh + t], s);
        atomicAdd(&s2sh[sh + C_W + t], sq);
    }
}

// ---------------- single-block scan (1024 thr x 32 elems, int4) ----------------
__global__ void __launch_bounds__(1024) k_scan(
        const int* __restrict__ counts, int* __restrict__ offsets,
        int* __restrict__ cursor) {
    __shared__ int sblk[1024];
    const int t = threadIdx.x;
    const int base = t * 32;
    const int4* cp = (const int4*)(counts + base);
    int loc[32];
    int s = 0;
    #pragma unroll
    for (int q = 0; q < 8; ++q) {
        int4 v = cp[q];
        loc[q*4+0] = s; s += v.x;
        loc[q*4+1] = s; s += v.y;
        loc[q*4+2] = s; s += v.z;
        loc[q*4+3] = s; s += v.w;
    }
    sblk[t] = s;
    __syncthreads();
    for (int d = 1; d < 1024; d <<= 1) {
        int u = (t >= d) ? sblk[t - d] : 0;
        __syncthreads();
        sblk[t] += u;
        __syncthreads();
    }
    const int blockbase = sblk[t] - s;
    #pragma unroll
    for (int q = 0; q < 8; ++q) {
        int4 o;
        o.x = blockbase + loc[q*4+0];
        o.y = blockbase + loc[q*4+1];
        o.z = blockbase + loc[q*4+2];
        o.w = blockbase + loc[q*4+3];
        ((int4*)(offsets + base))[q] = o;
        ((int4*)(cursor + base))[q] = o;
    }
    if (t == 1023) offsets[N_NODES] = sblk[1023];
}

// ---------------- scatter: CSR permutation of src indices ----------------
__global__ void __launch_bounds__(256) k_scatter(
        const int* __restrict__ ei, int E, int* __restrict__ cursor,
        int* __restrict__ srcPerm) {
    int e = blockIdx.x * 256 + threadIdx.x;
    if (e < E) {
        int dst = ei[E + e];
        int p = atomicAdd(&cursor[dst], 1);
        srcPerm[p] = ei[e];
    }
}

// ---------------- fused: WeightNet + aggregation + projection (+ BN3 stats) ----
__global__ void __launch_bounds__(512) k_node(
    const int* __restrict__ offsets, const int* __restrict__ srcPerm,
    const float* __restrict__ pos, const float* __restrict__ ori,
    const int* __restrict__ seq, const float* __restrict__ hpre,
    const float* __restrict__ s2sh, const float* __restrict__ g2,
    const float* __restrict__ b2,
    const float* __restrict__ wnw, const float* __restrict__ wnb,
    const float* __restrict__ convw,
    float* __restrict__ convout, float* __restrict__ s3sh) {

    __shared__ float sA2[C_W], sB2[C_W];
    __shared__ int sOff[GG + 1];
    __shared__ float sWnw[11 * WNS];
    __shared__ float sWnb[11 * WBS];
    __shared__ unsigned int sWp[GG][32 * EPS];   // packed bf16 w, padded stride
    __shared__ float sAgg[GG][AGS];
    __shared__ float sRed[8][GG][C_W];
    __shared__ float sRv[GG][C_W], sRq[GG][C_W];

    const int t = threadIdx.x;
    const int i0 = blockIdx.x * GG;
    for (int idx = t; idx < 11 * 168; idx += 512)
        sWnw[(idx / 168) * WNS + idx % 168] = wnw[idx];
    for (int idx = t; idx < 11 * 24; idx += 512)
        sWnb[(idx / 24) * WBS + idx % 24] = wnb[idx];
    if (t < C_W) {
        float s = 0.f, sq = 0.f;
        #pragma unroll
        for (int j = 0; j < 8; ++j) {
            s  += s2sh[j * 64 + t];
            sq += s2sh[j * 64 + C_W + t];
        }
        float mean = s * (1.f / N_NODES);
        float var = sq * (1.f / N_NODES) - mean * mean;
        float a = g2[t] * rsqrtf(var + 1e-5f);
        sA2[t] = a; sB2[t] = b2[t] - mean * a;
    }
    if (t <= GG) sOff[t] = offsets[i0 + t];
    __syncthreads();

    const int w = t >> 6, lane = t & 63, c = lane & 31, s = lane >> 5;
    const int i = i0 + w;
    const float bnA = sA2[c], bnB = sB2[c];
    const float pi0 = pos[i*3+0], pi1 = pos[i*3+1], pi2 = pos[i*3+2];
    float Rm[9];
    #pragma unroll
    for (int r = 0; r < 9; ++r) Rm[r] = ori[i*9+r];
    const int si = seq[i];
    const int beg = sOff[w], end = sOff[w + 1];
    unsigned int* sWw = &sWp[w][0];
    float a[12];
    #pragma unroll
    for (int j = 0; j < 12; ++j) a[j] = 0.f;

    for (int cb = beg; cb < end; cb += 32) {
        const int m = min(32, end - cb);
        const int src = srcPerm[cb + min(c, m - 1)];
        // ---- phase 1: delta + WeightNet + pack (wv/pk die before phase 2) ----
        {
            float px = pos[src*3+0], py = pos[src*3+1], pz = pos[src*3+2];
            float o0 = ori[src*9+0], o1 = ori[src*9+1], o2 = ori[src*9+2];
            int sqs = seq[src];
            float dx = px - pi0, dy = py - pi1, dz = pz - pi2;
            float dist = sqrtf(dx*dx + dy*dy + dz*dz);
            float inv = 1.f / (dist + 1e-9f);
            float ux = dx*inv, uy = dy*inv, uz = dz*inv;
            float df[7];
            df[0] = Rm[0]*ux + Rm[1]*uy + Rm[2]*uz;
            df[1] = Rm[3]*ux + Rm[4]*uy + Rm[5]*uz;
            df[2] = Rm[6]*ux + Rm[7]*uy + Rm[8]*uz;
            df[3] = Rm[0]*o0 + Rm[1]*o1 + Rm[2]*o2;
            df[4] = Rm[3]*o0 + Rm[4]*o1 + Rm[5]*o2;
            df[5] = Rm[6]*o0 + Rm[7]*o1 + Rm[8]*o2;
            df[6] = dist * 0.125f;
            int dsq = sqs - si; dsq = dsq < -SS ? -SS : (dsq > SS ? SS : dsq);
            const int sb = dsq + SS;
            float wv[12];
            {
                const float* wb = &sWnb[sb * WBS + s * 12];
                float4 b0 = *(const float4*)&wb[0];
                float4 b1 = *(const float4*)&wb[4];
                float4 b2_ = *(const float4*)&wb[8];
                wv[0]=b0.x; wv[1]=b0.y; wv[2]=b0.z; wv[3]=b0.w;
                wv[4]=b1.x; wv[5]=b1.y; wv[6]=b1.z; wv[7]=b1.w;
                wv[8]=b2_.x; wv[9]=b2_.y; wv[10]=b2_.z; wv[11]=b2_.w;
            }
            const float* wn = &sWnw[sb * WNS + s * 12];
            #pragma unroll
            for (int f = 0; f < 7; ++f) {
                float4 q0 = *(const float4*)&wn[f*24 + 0];
                float4 q1 = *(const float4*)&wn[f*24 + 4];
                float4 q2 = *(const float4*)&wn[f*24 + 8];
                float d_ = df[f];
                wv[0]+=d_*q0.x; wv[1]+=d_*q0.y; wv[2]+=d_*q0.z; wv[3]+=d_*q0.w;
                wv[4]+=d_*q1.x; wv[5]+=d_*q1.y; wv[6]+=d_*q1.z; wv[7]+=d_*q1.w;
                wv[8]+=d_*q2.x; wv[9]+=d_*q2.y; wv[10]+=d_*q2.z; wv[11]+=d_*q2.w;
            }
            #pragma unroll
            for (int j = 0; j < 12; ++j) wv[j] = wv[j] >= 0.f ? wv[j] : 0.2f * wv[j];
            unsigned int pk[6];
            #pragma unroll
            for (int jj = 0; jj < 6; ++jj) {
                unsigned int ulo = __float_as_uint(wv[2*jj]);
                unsigned int uhi = __float_as_uint(wv[2*jj+1]);
                ulo = (ulo + 0x7FFFu + ((ulo >> 16) & 1u)) >> 16;
                uhi = (uhi + 0x7FFFu + ((uhi >> 16) & 1u)) & 0xFFFF0000u;
                pk[jj] = uhi | ulo;
            }
            uint4 w4; w4.x = pk[0]; w4.y = pk[1]; w4.z = pk[2]; w4.w = pk[3];
            *(uint4*)&sWw[c * EPS + s * 8] = w4;
            uint2 w2_; w2_.x = pk[4]; w2_.y = pk[5];
            *(uint2*)&sWw[c * EPS + s * 8 + 4] = w2_;
        }
        // ---- phase 2: h preload (16 independent gathers) ----
        float hr[16];
        #pragma unroll
        for (int q = 0; q < 16; ++q) {
            int ee = min(2 * q + s, m - 1);
            int sq_ = __shfl(src, ee, 32);
            hr[q] = hpre[(size_t)sq_ * C_W + c];
        }
        #pragma unroll
        for (int q = 0; q < 16; ++q) {
            float v = bnA * hr[q] + bnB;
            v = v >= 0.f ? v : 0.1f * v;
            hr[q] = (2 * q + s < m) ? v : 0.f;
        }
        // ---- phase 3: FMA over 32 edges ----
        #pragma unroll
        for (int q = 0; q < 16; ++q) {
            float oth = __shfl_xor(hr[q], 32);
            float v0 = (s == 0) ? hr[q] : oth;   // edge 2q
            float v1 = (s == 0) ? oth : hr[q];   // edge 2q+1
            {
                uint4 pA = *(const uint4*)&sWw[(2*q) * EPS + s * 8];
                uint2 pB = *(const uint2*)&sWw[(2*q) * EPS + s * 8 + 4];
                a[0]  += __uint_as_float(pA.x << 16) * v0;
                a[1]  += __uint_as_float(pA.x & 0xFFFF0000u) * v0;
                a[2]  += __uint_as_float(pA.y << 16) * v0;
                a[3]  += __uint_as_float(pA.y & 0xFFFF0000u) * v0;
                a[4]  += __uint_as_float(pA.z << 16) * v0;
                a[5]  += __uint_as_float(pA.z & 0xFFFF0000u) * v0;
                a[6]  += __uint_as_float(pA.w << 16) * v0;
                a[7]  += __uint_as_float(pA.w & 0xFFFF0000u) * v0;
                a[8]  += __uint_as_float(pB.x << 16) * v0;
                a[9]  += __uint_as_float(pB.x & 0xFFFF0000u) * v0;
                a[10] += __uint_as_float(pB.y << 16) * v0;
                a[11] += __uint_as_float(pB.y & 0xFFFF0000u) * v0;
            }
            {
                uint4 pA = *(const uint4*)&sWw[(2*q+1) * EPS + s * 8];
                uint2 pB = *(const uint2*)&sWw[(2*q+1) * EPS + s * 8 + 4];
                a[0]  += __uint_as_float(pA.x << 16) * v1;
                a[1]  += __uint_as_float(pA.x & 0xFFFF0000u) * v1;
                a[2]  += __uint_as_float(pA.y << 16) * v1;
                a[3]  += __uint_as_float(pA.y & 0xFFFF0000u) * v1;
                a[4]  += __uint_as_float(pA.z << 16) * v1;
                a[5]  += __uint_as_float(pA.z & 0xFFFF0000u) * v1;
                a[6]  += __uint_as_float(pA.w << 16) * v1;
                a[7]  += __uint_as_float(pA.w & 0xFFFF0000u) * v1;
                a[8]  += __uint_as_float(pB.x << 16) * v1;
                a[9]  += __uint_as_float(pB.x & 0xFFFF0000u) * v1;
                a[10] += __uint_as_float(pB.y << 16) * v1;
                a[11] += __uint_as_float(pB.y & 0xFFFF0000u) * v1;
            }
        }
    }
    #pragma unroll
    for (int j = 0; j < 12; ++j) sAgg[w][(s * 12 + j) * C_W + c] = a[j];
    __syncthreads();

    // projection: t = sl8*64 + gp*8 + coq ; each thread 96 rows x 4 cols
    {
        const int coq = t & 7;
        const int gp  = (t >> 3) & 7;
        const int sl8 = t >> 6;
        const int r0  = sl8 * 96;
        float4 acc; acc.x = acc.y = acc.z = acc.w = 0.f;
        #pragma unroll 6
        for (int rc = 0; rc < 96; rc += 4) {
            const float4 s4 = *(const float4*)&sAgg[gp][r0 + rc];
            const float4 w0 = *(const float4*)&convw[(size_t)(r0+rc+0)*32 + coq*4];
            const float4 w1 = *(const float4*)&convw[(size_t)(r0+rc+1)*32 + coq*4];
            const float4 w2 = *(const float4*)&convw[(size_t)(r0+rc+2)*32 + coq*4];
            const float4 w3 = *(const float4*)&convw[(size_t)(r0+rc+3)*32 + coq*4];
            acc.x += s4.x*w0.x + s4.y*w1.x + s4.z*w2.x + s4.w*w3.x;
            acc.y += s4.x*w0.y + s4.y*w1.y + s4.z*w2.y + s4.w*w3.y;
            acc.z += s4.x*w0.z + s4.y*w1.z + s4.z*w2.z + s4.w*w3.z;
            acc.w += s4.x*w0.w + s4.y*w1.w + s4.z*w2.w + s4.w*w3.w;
        }
        *(float4*)&sRed[sl8][gp][coq * 4] = acc;
    }
    __syncthreads();
    if (t < 256) {
        const int gg = t >> 5, co = t & 31;
        float v = 0.f;
        #pragma unroll
        for (int sl = 0; sl < 8; ++sl) v += sRed[sl][gg][co];
        convout[(size_t)(i0 + gg) * C_W + co] = v;
        sRv[gg][co] = v; sRq[gg][co] = v * v;
    }
    __syncthreads();
    if (t < 64) {
        int cc = t & 31;
        bool isq = t >= C_W;
        float s2 = 0.f;
        #pragma unroll
        for (int gg = 0; gg < GG; ++gg)
            s2 += isq ? sRq[gg][cc] : sRv[gg][cc];
        atomicAdd(&s3sh[(blockIdx.x & 7) * 64 + t], s2);
    }
}

// ---------------- output: lrelu(bn3(conv)) @ lin2_w + x (float4) ----------------
__global__ void __launch_bounds__(256) k_out(
        const float* __restrict__ conv, const float* __restrict__ s3sh,
        const float* __restrict__ g3, const float* __restrict__ b3,
        const float* __restrict__ w2, const float* __restrict__ x,
        float* __restrict__ out) {
    __shared__ float sAB[2][C_W];
    __shared__ float sh[8][C_W];
    __shared__ float sw2[C_W][C_IN];
    const int t = threadIdx.x;
    const int row0 = blockIdx.x * 8;
    if (t < C_W) {
        float s = 0.f, sq = 0.f;
        #pragma unroll
        for (int j = 0; j < 8; ++j) {
            s  += s3sh[j * 64 + t];
            sq += s3sh[j * 64 + C_W + t];
        }
        float mean = s * (1.f / N_NODES);
        float var = sq * (1.f / N_NODES) - mean * mean;
        float a = g3[t] * rsqrtf(var + 1e-5f);
        sAB[0][t] = a; sAB[1][t] = b3[t] - mean * a;
    }
    for (int idx = t; idx < C_W * C_IN; idx += 256)
        sw2[idx >> 7][idx & 127] = w2[idx];
    __syncthreads();
    {
        float v = conv[(size_t)row0 * C_W + t];
        int r = t >> 5, cc = t & 31;
        v = sAB[0][cc] * v + sAB[1][cc];
        sh[r][cc] = v >= 0.f ? v : 0.1f * v;
    }
    __syncthreads();
    const int r = t >> 5, c4 = (t & 31) * 4;
    float4 acc = *(const float4*)&x[(size_t)(row0 + r) * C_IN + c4];
    #pragma unroll 8
    for (int cw = 0; cw < C_W; ++cw) {
        float hv = sh[r][cw];
        float4 wv = *(const float4*)&sw2[cw][c4];
        acc.x += hv * wv.x; acc.y += hv * wv.y;
        acc.z += hv * wv.z; acc.w += hv * wv.w;
    }
    *(float4*)&out[(size_t)(row0 + r) * C_IN + c4] = acc;
}

extern "C" void kernel_launch(void* const* d_in, const int* in_sizes, int n_in,
                              void* d_out, int out_size, void* d_ws, size_t ws_size,
                              hipStream_t stream) {
    const float* x     = (const float*)d_in[0];
    const float* pos   = (const float*)d_in[1];
    const float* ori   = (const float*)d_in[2];
    const int*   seq   = (const int*)d_in[3];
    const int*   ei    = (const int*)d_in[4];
    const float* bn1g  = (const float*)d_in[5];
    const float* bn1b  = (const float*)d_in[6];
    const float* lin1w = (const float*)d_in[7];
    const float* bn2g  = (const float*)d_in[8];
    const float* bn2b  = (const float*)d_in[9];
    const float* wnw   = (const float*)d_in[10];
    const float* wnb   = (const float*)d_in[11];
    const float* convw = (const float*)d_in[12];
    const float* bn3g  = (const float*)d_in[13];
    const float* bn3b  = (const float*)d_in[14];
    const float* lin2w = (const float*)d_in[15];
    float* out = (float*)d_out;
    const int E = in_sizes[4] / 2;

    char* wsb = (char*)d_ws;
    size_t off = 0;
    auto alloc = [&](size_t bytes) {
        void* p = wsb + off;
        off = (off + bytes + 255) & ~(size_t)255;
        return p;
    };
    float* s1      = (float*)alloc(256 * 4);
    float* s2sh    = (float*)alloc(512 * 4);
    float* s3sh    = (float*)alloc(512 * 4);
    int*   counts  = (int*)alloc((size_t)N_NODES * 4);
    size_t zero_bytes = off;
    int*   offsets = (int*)alloc(((size_t)N_NODES + 1) * 4);
    int*   cursor  = (int*)alloc((size_t)N_NODES * 4);
    int*   srcPerm = (int*)alloc((size_t)E * 4);
    float* hpre    = (float*)alloc((size_t)N_NODES * C_W * 4);
    float* convo   = (float*)alloc((size_t)N_NODES * C_W * 4);

    hipMemsetAsync(wsb, 0, zero_bytes, stream);

    k_pre<<<512, 256, 0, stream>>>(x, s1, ei, E, counts);
    k_scan<<<1, 1024, 0, stream>>>(counts, offsets, cursor);
    k_scatter<<<(E + 255) / 256, 256, 0, stream>>>(ei, E, cursor, srcPerm);
    k_mlp1<<<N_NODES / 32, 256, 0, stream>>>(x, s1, bn1g, bn1b, lin1w, hpre, s2sh);
    k_node<<<N_NODES / GG, 512, 0, stream>>>(offsets, srcPerm, pos, ori, seq,
                                             hpre, s2sh, bn2g, bn2b, wnw, wnb,
                                             convw, convo, s3sh);
    k_out<<<N_NODES / 8, 256, 0, stream>>>(convo, s3sh, bn3g, bn3b, lin2w, x, out);
}

// Round 11
// 310.206 us; speedup vs baseline: 1.8939x; 1.4548x over previous
//
#include <hip/hip_runtime.h>

#define N_NODES 32768
#define C_IN 128
#define C_W 32
#define KK 24
#define SS 5
#define GG 8                 // nodes per k_node block (one per wave)
#define AGS (KK * C_W + 4)   // padded sAgg stride
#define TCAP 256             // staged edges per tranche

// ---------------- colstats(x) for BN1 + edge histogram ----------------
__global__ void __launch_bounds__(256) k_pre(
        const float* __restrict__ x, float* __restrict__ s1,
        const int* __restrict__ ei, int E, int* __restrict__ counts) {
    int t = threadIdx.x;
    int c = t % C_IN;
    int r0 = blockIdx.x * 2 + t / C_IN;
    float s = 0.f, sq = 0.f;
    for (int r = r0; r < N_NODES; r += 1024) {
        float v = x[(size_t)r * C_IN + c];
        s += v; sq += v * v;
    }
    atomicAdd(&s1[c], s);
    atomicAdd(&s1[C_IN + c], sq);
    for (int e = blockIdx.x * 256 + t; e < E; e += 512 * 256)
        atomicAdd(&counts[ei[E + e]], 1);
}

// ---------------- input MLP: lrelu(bn1(x)) @ lin1_w (+ BN2 stats) ----------------
__global__ void __launch_bounds__(256) k_mlp1(
        const float* __restrict__ x, const float* __restrict__ s1,
        const float* __restrict__ g1, const float* __restrict__ b1,
        const float* __restrict__ w1, float* __restrict__ hpre,
        float* __restrict__ s2sh) {
    __shared__ float sAB[2][C_IN];
    __shared__ float sx[32][C_IN + 4];
    __shared__ float sw[C_IN][C_W];
    const int t = threadIdx.x;
    const int row0 = blockIdx.x * 32;
    if (t < C_IN) {
        float mean = s1[t] * (1.f / N_NODES);
        float var = s1[C_IN + t] * (1.f / N_NODES) - mean * mean;
        float a = g1[t] * rsqrtf(var + 1e-5f);
        sAB[0][t] = a; sAB[1][t] = b1[t] - mean * a;
    }
    for (int idx = t; idx < C_IN * C_W; idx += 256)
        sw[idx / C_W][idx % C_W] = w1[idx];
    __syncthreads();
    for (int idx = t; idx < 32 * 32; idx += 256) {
        int r = idx >> 5, cq = idx & 31;
        float4 v = *(const float4*)&x[(size_t)(row0 + r) * C_IN + cq * 4];
        float* d = &sx[r][cq * 4];
        float a0 = sAB[0][cq*4+0]*v.x + sAB[1][cq*4+0];
        float a1 = sAB[0][cq*4+1]*v.y + sAB[1][cq*4+1];
        float a2 = sAB[0][cq*4+2]*v.z + sAB[1][cq*4+2];
        float a3 = sAB[0][cq*4+3]*v.w + sAB[1][cq*4+3];
        d[0] = a0 >= 0.f ? a0 : 0.1f * a0;
        d[1] = a1 >= 0.f ? a1 : 0.1f * a1;
        d[2] = a2 >= 0.f ? a2 : 0.1f * a2;
        d[3] = a3 >= 0.f ? a3 : 0.1f * a3;
    }
    __syncthreads();
    const int r = t >> 3, c0 = (t & 7) * 4;
    float ac0 = 0.f, ac1 = 0.f, ac2 = 0.f, ac3 = 0.f;
    #pragma unroll 8
    for (int cc = 0; cc < C_IN; ++cc) {
        float xv = sx[r][cc];
        float4 wv = *(const float4*)&sw[cc][c0];
        ac0 += xv * wv.x; ac1 += xv * wv.y; ac2 += xv * wv.z; ac3 += xv * wv.w;
    }
    float4 o; o.x = ac0; o.y = ac1; o.z = ac2; o.w = ac3;
    *(float4*)&hpre[(size_t)(row0 + r) * C_W + c0] = o;
    __syncthreads();
    sx[r][c0] = ac0; sx[r][c0+1] = ac1; sx[r][c0+2] = ac2; sx[r][c0+3] = ac3;
    __syncthreads();
    if (t < C_W) {
        float s = 0.f, sq = 0.f;
        #pragma unroll
        for (int rr = 0; rr < 32; ++rr) {
            float v = sx[rr][t];
            s += v; sq += v * v;
        }
        int sh = (blockIdx.x & 7) * 64;
        atomicAdd(&s2sh[sh + t], s);
        atomicAdd(&s2sh[sh + C_W + t], sq);
    }
}

// ---------------- single-block scan (1024 thr x 32 elems, int4) ----------------
__global__ void __launch_bounds__(1024) k_scan(
        const int* __restrict__ counts, int* __restrict__ offsets,
        int* __restrict__ cursor) {
    __shared__ int sblk[1024];
    const int t = threadIdx.x;
    const int base = t * 32;
    const int4* cp = (const int4*)(counts + base);
    int loc[32];
    int s = 0;
    #pragma unroll
    for (int q = 0; q < 8; ++q) {
        int4 v = cp[q];
        loc[q*4+0] = s; s += v.x;
        loc[q*4+1] = s; s += v.y;
        loc[q*4+2] = s; s += v.z;
        loc[q*4+3] = s; s += v.w;
    }
    sblk[t] = s;
    __syncthreads();
    for (int d = 1; d < 1024; d <<= 1) {
        int u = (t >= d) ? sblk[t - d] : 0;
        __syncthreads();
        sblk[t] += u;
        __syncthreads();
    }
    const int blockbase = sblk[t] - s;
    #pragma unroll
    for (int q = 0; q < 8; ++q) {
        int4 o;
        o.x = blockbase + loc[q*4+0];
        o.y = blockbase + loc[q*4+1];
        o.z = blockbase + loc[q*4+2];
        o.w = blockbase + loc[q*4+3];
        ((int4*)(offsets + base))[q] = o;
        ((int4*)(cursor + base))[q] = o;
    }
    if (t == 1023) offsets[N_NODES] = sblk[1023];
}

// ---------------- edge kernel: WeightNet + bf16 pack + scatter to CSR ----------------
__global__ void __launch_bounds__(256) k_edge(
        const int* __restrict__ ei, int E,
        const float* __restrict__ pos, const float* __restrict__ ori,
        const int* __restrict__ seq,
        const float* __restrict__ wnw, const float* __restrict__ wnb,
        int* __restrict__ cursor, int* __restrict__ srcPerm,
        unsigned int* __restrict__ wPerm) {
    __shared__ float sWnw[11][169];
    __shared__ float sWnb[11][24];
    const int t = threadIdx.x;
    for (int idx = t; idx < 11 * 168; idx += 256)
        sWnw[idx / 168][idx % 168] = wnw[idx];
    for (int idx = t; idx < 11 * 24; idx += 256)
        sWnb[idx / 24][idx % 24] = wnb[idx];
    __syncthreads();
    const int e = blockIdx.x * 256 + t;
    if (e >= E) return;
    const int src = ei[e];
    const int dst = ei[E + e];
    int ds = seq[src] - seq[dst];
    ds = ds < -SS ? -SS : (ds > SS ? SS : ds);
    const int sb = ds + SS;
    float dx = pos[src * 3 + 0] - pos[dst * 3 + 0];
    float dy = pos[src * 3 + 1] - pos[dst * 3 + 1];
    float dz = pos[src * 3 + 2] - pos[dst * 3 + 2];
    float dist = sqrtf(dx * dx + dy * dy + dz * dz);
    float inv = 1.f / (dist + 1e-9f);
    float ux = dx * inv, uy = dy * inv, uz = dz * inv;
    float b0 = ori[src * 9 + 0], b1 = ori[src * 9 + 1], b2 = ori[src * 9 + 2];
    float delta[7];
    #pragma unroll
    for (int r = 0; r < 3; ++r) {
        float m0 = ori[dst * 9 + r * 3 + 0];
        float m1 = ori[dst * 9 + r * 3 + 1];
        float m2 = ori[dst * 9 + r * 3 + 2];
        delta[r]     = m0 * ux + m1 * uy + m2 * uz;
        delta[3 + r] = m0 * b0 + m1 * b1 + m2 * b2;
    }
    delta[6] = dist * 0.125f;
    float w[KK];
    #pragma unroll
    for (int k = 0; k < KK; ++k) {
        float acc = sWnb[sb][k];
        #pragma unroll
        for (int f = 0; f < 7; ++f)
            acc += delta[f] * sWnw[sb][f * 24 + k];
        w[k] = acc >= 0.f ? acc : 0.2f * acc;
    }
    const int p = atomicAdd(&cursor[dst], 1);
    srcPerm[p] = src;
    unsigned int pk[12];
    #pragma unroll
    for (int jj = 0; jj < 12; ++jj) {
        unsigned int ulo = __float_as_uint(w[2*jj]);
        unsigned int uhi = __float_as_uint(w[2*jj+1]);
        ulo = (ulo + 0x7FFFu + ((ulo >> 16) & 1u)) >> 16;
        uhi = (uhi + 0x7FFFu + ((uhi >> 16) & 1u)) & 0xFFFF0000u;
        pk[jj] = uhi | ulo;
    }
    uint4* wp = (uint4*)(wPerm + (size_t)p * 12);
    uint4 o0; o0.x = pk[0]; o0.y = pk[1]; o0.z = pk[2]; o0.w = pk[3];
    uint4 o1; o1.x = pk[4]; o1.y = pk[5]; o1.z = pk[6]; o1.w = pk[7];
    uint4 o2; o2.x = pk[8]; o2.y = pk[9]; o2.z = pk[10]; o2.w = pk[11];
    wp[0] = o0; wp[1] = o1; wp[2] = o2;
}

#define BF_LO(u) __uint_as_float((u) << 16)
#define BF_HI(u) __uint_as_float((u) & 0xFFFF0000u)

// ---------------- aggregation + conv projection (+ BN3 stats) ----------------
// 512 threads = 8 waves; one node per wave. Block-wide burst staging of the
// full 8-node CSR span (wPerm bf16 + srcPerm) into LDS, then latency-free
// compute from LDS with 4-deep hpre gather ILP.
__global__ void __launch_bounds__(512) k_node(
    const int* __restrict__ offsets, const int* __restrict__ srcPerm,
    const unsigned int* __restrict__ wPerm, const float* __restrict__ hpre,
    const float* __restrict__ s2sh, const float* __restrict__ g2,
    const float* __restrict__ b2, const float* __restrict__ convw,
    float* __restrict__ convout, float* __restrict__ s3sh) {

    __shared__ float sA2[C_W], sB2[C_W];
    __shared__ int sOff[GG + 1];
    __shared__ float sAgg[GG][AGS];
    __shared__ union SU {
        struct { unsigned int w[TCAP * 12]; int src[TCAP]; } stg;      // 13KB
        struct { float red[8][GG][C_W]; float rv[GG][C_W]; float rq[GG][C_W]; } fin; // 10KB
    } U;

    const int t = threadIdx.x;
    const int i0 = blockIdx.x * GG;
    if (t < C_W) {
        float s = 0.f, sq = 0.f;
        #pragma unroll
        for (int j = 0; j < 8; ++j) {
            s  += s2sh[j * 64 + t];
            sq += s2sh[j * 64 + C_W + t];
        }
        float mean = s * (1.f / N_NODES);
        float var = sq * (1.f / N_NODES) - mean * mean;
        float a = g2[t] * rsqrtf(var + 1e-5f);
        sA2[t] = a; sB2[t] = b2[t] - mean * a;
    }
    if (t <= GG) sOff[t] = offsets[i0 + t];
    __syncthreads();

    const int w = t >> 6, lane = t & 63, c = lane & 31, s = lane >> 5;
    const float bnA = sA2[c], bnB = sB2[c];
    const int beg = sOff[w], end = sOff[w + 1];
    const int blkBeg = sOff[0], blkEnd = sOff[GG];
    float a[KK];
    #pragma unroll
    for (int k = 0; k < KK; ++k) a[k] = 0.f;

    for (int base = blkBeg; base < blkEnd; base += TCAP) {
        const int cnt = min(TCAP, blkEnd - base);
        __syncthreads();   // previous tranche fully consumed
        {
            const uint4* gw = (const uint4*)(wPerm + (size_t)base * 12);
            uint4* lw = (uint4*)U.stg.w;
            for (int u = t; u < cnt * 3; u += 512) lw[u] = gw[u];
            if (t < cnt) U.stg.src[t] = srcPerm[base + t];
        }
        __syncthreads();
        const int lo = max(beg, base) - base;
        const int hi = min(end, base + cnt) - base;
        for (int j8 = lo; j8 < hi; j8 += 8) {
            const int last = hi - 1;
            const int e0 = j8 + 0 + s, e1 = j8 + 2 + s;
            const int e2 = j8 + 4 + s, e3 = j8 + 6 + s;
            // 4 independent gathers in flight (src from LDS, broadcast)
            const int s0 = U.stg.src[min(e0, last)];
            const int s1 = U.stg.src[min(e1, last)];
            const int s2_ = U.stg.src[min(e2, last)];
            const int s3_ = U.stg.src[min(e3, last)];
            float h0 = hpre[(size_t)s0 * C_W + c];
            float h1 = hpre[(size_t)s1 * C_W + c];
            float h2 = hpre[(size_t)s2_ * C_W + c];
            float h3 = hpre[(size_t)s3_ * C_W + c];
            h0 = bnA*h0 + bnB; h0 = h0 >= 0.f ? h0 : 0.1f*h0; h0 = (e0 < hi) ? h0 : 0.f;
            h1 = bnA*h1 + bnB; h1 = h1 >= 0.f ? h1 : 0.1f*h1; h1 = (e1 < hi) ? h1 : 0.f;
            h2 = bnA*h2 + bnB; h2 = h2 >= 0.f ? h2 : 0.1f*h2; h2 = (e2 < hi) ? h2 : 0.f;
            h3 = bnA*h3 + bnB; h3 = h3 >= 0.f ? h3 : 0.1f*h3; h3 = (e3 < hi) ? h3 : 0.f;
            #pragma unroll
            for (int q = 0; q < 4; ++q) {
                const float v = q == 0 ? h0 : (q == 1 ? h1 : (q == 2 ? h2 : h3));
                const int ee = min(j8 + 2 * q + s, last);
                const uint4* wp = (const uint4*)&U.stg.w[ee * 12];
                const uint4 A = wp[0], B = wp[1], Cc = wp[2];
                a[0]  += BF_LO(A.x) * v;  a[1]  += BF_HI(A.x) * v;
                a[2]  += BF_LO(A.y) * v;  a[3]  += BF_HI(A.y) * v;
                a[4]  += BF_LO(A.z) * v;  a[5]  += BF_HI(A.z) * v;
                a[6]  += BF_LO(A.w) * v;  a[7]  += BF_HI(A.w) * v;
                a[8]  += BF_LO(B.x) * v;  a[9]  += BF_HI(B.x) * v;
                a[10] += BF_LO(B.y) * v;  a[11] += BF_HI(B.y) * v;
                a[12] += BF_LO(B.z) * v;  a[13] += BF_HI(B.z) * v;
                a[14] += BF_LO(B.w) * v;  a[15] += BF_HI(B.w) * v;
                a[16] += BF_LO(Cc.x) * v; a[17] += BF_HI(Cc.x) * v;
                a[18] += BF_LO(Cc.y) * v; a[19] += BF_HI(Cc.y) * v;
                a[20] += BF_LO(Cc.z) * v; a[21] += BF_HI(Cc.z) * v;
                a[22] += BF_LO(Cc.w) * v; a[23] += BF_HI(Cc.w) * v;
            }
        }
    }
    // fold the two halves (they covered even/odd edges)
    #pragma unroll
    for (int k = 0; k < KK; ++k) a[k] += __shfl_xor(a[k], 32, 64);
    if (s == 0) {
        #pragma unroll
        for (int k = 0; k < KK; ++k) sAgg[w][k * C_W + c] = a[k];
    }
    __syncthreads();

    // projection: t = sl8*64 + gp*8 + coq ; each thread 96 rows x 4 cols
    {
        const int coq = t & 7;
        const int gp  = (t >> 3) & 7;
        const int sl8 = t >> 6;
        const int r0  = sl8 * 96;
        float4 acc; acc.x = acc.y = acc.z = acc.w = 0.f;
        #pragma unroll 6
        for (int rc = 0; rc < 96; rc += 4) {
            const float4 s4 = *(const float4*)&sAgg[gp][r0 + rc];
            const float4 w0 = *(const float4*)&convw[(size_t)(r0+rc+0)*32 + coq*4];
            const float4 w1 = *(const float4*)&convw[(size_t)(r0+rc+1)*32 + coq*4];
            const float4 w2 = *(const float4*)&convw[(size_t)(r0+rc+2)*32 + coq*4];
            const float4 w3 = *(const float4*)&convw[(size_t)(r0+rc+3)*32 + coq*4];
            acc.x += s4.x*w0.x + s4.y*w1.x + s4.z*w2.x + s4.w*w3.x;
            acc.y += s4.x*w0.y + s4.y*w1.y + s4.z*w2.y + s4.w*w3.y;
            acc.z += s4.x*w0.z + s4.y*w1.z + s4.z*w2.z + s4.w*w3.z;
            acc.w += s4.x*w0.w + s4.y*w1.w + s4.z*w2.w + s4.w*w3.w;
        }
        *(float4*)&U.fin.red[sl8][gp][coq * 4] = acc;
    }
    __syncthreads();
    if (t < 256) {
        const int gg = t >> 5, co = t & 31;
        float v = 0.f;
        #pragma unroll
        for (int sl = 0; sl < 8; ++sl) v += U.fin.red[sl][gg][co];
        convout[(size_t)(i0 + gg) * C_W + co] = v;
        U.fin.rv[gg][co] = v; U.fin.rq[gg][co] = v * v;
    }
    __syncthreads();
    if (t < 64) {
        int cc = t & 31;
        bool isq = t >= C_W;
        float s2 = 0.f;
        #pragma unroll
        for (int gg = 0; gg < GG; ++gg)
            s2 += isq ? U.fin.rq[gg][cc] : U.fin.rv[gg][cc];
        atomicAdd(&s3sh[(blockIdx.x & 7) * 64 + t], s2);
    }
}

// ---------------- output: lrelu(bn3(conv)) @ lin2_w + x (float4) ----------------
__global__ void __launch_bounds__(256) k_out(
        const float* __restrict__ conv, const float* __restrict__ s3sh,
        const float* __restrict__ g3, const float* __restrict__ b3,
        const float* __restrict__ w2, const float* __restrict__ x,
        float* __restrict__ out) {
    __shared__ float sAB[2][C_W];
    __shared__ float sh[8][C_W];
    __shared__ float sw2[C_W][C_IN];
    const int t = threadIdx.x;
    const int row0 = blockIdx.x * 8;
    if (t < C_W) {
        float s = 0.f, sq = 0.f;
        #pragma unroll
        for (int j = 0; j < 8; ++j) {
            s  += s3sh[j * 64 + t];
            sq += s3sh[j * 64 + C_W + t];
        }
        float mean = s * (1.f / N_NODES);
        float var = sq * (1.f / N_NODES) - mean * mean;
        float a = g3[t] * rsqrtf(var + 1e-5f);
        sAB[0][t] = a; sAB[1][t] = b3[t] - mean * a;
    }
    for (int idx = t; idx < C_W * C_IN; idx += 256)
        sw2[idx >> 7][idx & 127] = w2[idx];
    __syncthreads();
    {
        float v = conv[(size_t)row0 * C_W + t];
        int r = t >> 5, cc = t & 31;
        v = sAB[0][cc] * v + sAB[1][cc];
        sh[r][cc] = v >= 0.f ? v : 0.1f * v;
    }
    __syncthreads();
    const int r = t >> 5, c4 = (t & 31) * 4;
    float4 acc = *(const float4*)&x[(size_t)(row0 + r) * C_IN + c4];
    #pragma unroll 8
    for (int cw = 0; cw < C_W; ++cw) {
        float hv = sh[r][cw];
        float4 wv = *(const float4*)&sw2[cw][c4];
        acc.x += hv * wv.x; acc.y += hv * wv.y;
        acc.z += hv * wv.z; acc.w += hv * wv.w;
    }
    *(float4*)&out[(size_t)(row0 + r) * C_IN + c4] = acc;
}

extern "C" void kernel_launch(void* const* d_in, const int* in_sizes, int n_in,
                              void* d_out, int out_size, void* d_ws, size_t ws_size,
                              hipStream_t stream) {
    const float* x     = (const float*)d_in[0];
    const float* pos   = (const float*)d_in[1];
    const float* ori   = (const float*)d_in[2];
    const int*   seq   = (const int*)d_in[3];
    const int*   ei    = (const int*)d_in[4];
    const float* bn1g  = (const float*)d_in[5];
    const float* bn1b  = (const float*)d_in[6];
    const float* lin1w = (const float*)d_in[7];
    const float* bn2g  = (const float*)d_in[8];
    const float* bn2b  = (const float*)d_in[9];
    const float* wnw   = (const float*)d_in[10];
    const float* wnb   = (const float*)d_in[11];
    const float* convw = (const float*)d_in[12];
    const float* bn3g  = (const float*)d_in[13];
    const float* bn3b  = (const float*)d_in[14];
    const float* lin2w = (const float*)d_in[15];
    float* out = (float*)d_out;
    const int E = in_sizes[4] / 2;

    char* wsb = (char*)d_ws;
    size_t off = 0;
    auto alloc = [&](size_t bytes) {
        void* p = wsb + off;
        off = (off + bytes + 255) & ~(size_t)255;
        return p;
    };
    float* s1      = (float*)alloc(256 * 4);
    float* s2sh    = (float*)alloc(512 * 4);
    float* s3sh    = (float*)alloc(512 * 4);
    int*   counts  = (int*)alloc((size_t)N_NODES * 4);
    size_t zero_bytes = off;
    int*   offsets = (int*)alloc(((size_t)N_NODES + 1) * 4);
    int*   cursor  = (int*)alloc((size_t)N_NODES * 4);
    int*   srcPerm = (int*)alloc((size_t)E * 4);
    float* hpre    = (float*)alloc((size_t)N_NODES * C_W * 4);
    float* convo   = (float*)alloc((size_t)N_NODES * C_W * 4);
    unsigned int* wPerm = (unsigned int*)alloc((size_t)E * 12 * 4);

    hipMemsetAsync(wsb, 0, zero_bytes, stream);

    k_pre<<<512, 256, 0, stream>>>(x, s1, ei, E, counts);
    k_scan<<<1, 1024, 0, stream>>>(counts, offsets, cursor);
    k_edge<<<(E + 255) / 256, 256, 0, stream>>>(ei, E, pos, ori, seq, wnw, wnb,
                                                cursor, srcPerm, wPerm);
    k_mlp1<<<N_NODES / 32, 256, 0, stream>>>(x, s1, bn1g, bn1b, lin1w, hpre, s2sh);
    k_node<<<N_NODES / GG, 512, 0, stream>>>(offsets, srcPerm, wPerm, hpre,
                                             s2sh, bn2g, bn2b, convw, convo, s3sh);
    k_out<<<N_NODES / 8, 256, 0, stream>>>(convo, s3sh, bn3g, bn3b, lin2w, x, out);
}